// Round 19
// baseline (75.703 us; speedup 1.0000x reference)
//
#include <hip/hip_runtime.h>
#include <hip/hip_bf16.h>
#include <stdint.h>

// KANLinear: y[b,o] = sum_{d,k} coeff[b,d,k]*values[o,d,k] + xc@skip_w^T + skip_b
//   Vp[o,d*16+k] = values[o,d,k] + grid[k]*skip_w[o,d]   (prep, bf16)
//   y = A @ Vp^T + skip_b  (MFMA GEMM  M=8192 N=256 K=4096)
// Round 19: ZERO-LDS GEMM. R16 probes: vm-only stream (P1) and lgkm-fed
//   MFMA (P2) each hit the exact MFMA floor; combined = 2.45x. The only
//   element unique to the full kernel: MFMA waits on BOTH counters. Fix:
//   A-fragments built ENTIRELY in registers (R4's proven mkfrag decode,
//   x via aligned float4 loads - vmcnt only). No ds ops, no barriers, no
//   pins anywhere. BM=64 BN=256 KS=4, 512 blocks, 3-buf 2-deep B.

#define D_DIM  256
#define O_DIM  256
#define BM     64
#define KS     4
#define ITERS  16             // (4096/KS)/BK, BK=64 (4 d's per iter)
#define NTHR   256

typedef __attribute__((ext_vector_type(8))) short bf16x8;
typedef __attribute__((ext_vector_type(4))) float f32x4;

// ---------------------------------------------------------------------------
// Prep (proven) + x-warm. Vp chunk-transposed: chunk c = kflat>>3 at
// Vp[(c*256 + o)*8] -> B-fragment loads 256B-coalesced.
// ---------------------------------------------------------------------------
__global__ __launch_bounds__(256) void kan_prep(
    const float* __restrict__ values,   // [O][D][K]
    const float* __restrict__ skip_w,   // [O][D]
    const float* __restrict__ gknots,   // [K]
    const float* __restrict__ x,        // [B][D] (warm only)
    unsigned short* __restrict__ Vp)    // 2 MB bf16, chunk-transposed
{
    int tid = blockIdx.x * blockDim.x + threadIdx.x;    // 0..131071
    int e = tid * 8;
    int o = e >> 12;
    int kflat = e & 4095;
    float sw = skip_w[(o << 8) | (kflat >> 4)];
    int kmod = kflat & 15;                              // 0 or 8

    const float4* vp4 = reinterpret_cast<const float4*>(values + e);
    float4 v0 = vp4[0], v1 = vp4[1];
    float f[8] = {v0.x, v0.y, v0.z, v0.w, v1.x, v1.y, v1.z, v1.w};
    unsigned int w[4];
#pragma unroll
    for (int j = 0; j < 4; ++j) {
        float2 ab;
        ab.x = f[2*j]     + gknots[kmod + 2*j]     * sw;
        ab.y = f[2*j + 1] + gknots[kmod + 2*j + 1] * sw;
        __hip_bfloat162 p2 = __float22bfloat162_rn(ab);
        __builtin_memcpy(&w[j], &p2, 4);
    }
    size_t c = (size_t)(kflat >> 3) * 256 + (size_t)o;
    *reinterpret_cast<uint4*>(Vp + c * 8) = make_uint4(w[0], w[1], w[2], w[3]);

    // x-warm: XCD pb%8 touches x rows of its gemm blocks (mt===pb%8).
    {
        int pb = (int)blockIdx.x;
        int mt = (pb & 7) + 8 * ((pb >> 3) & 15);       // 0..127
        int rowbase = mt * BM + (pb >> 7) * 16;         // 16-row stripe
        int t = (int)threadIdx.x;
        const float4* xw = reinterpret_cast<const float4*>(
            x + (size_t)(rowbase + (t >> 4)) * D_DIM) + (t & 15) * 4;
        float s = 0.f;
#pragma unroll
        for (int k = 0; k < 4; ++k) {
            float4 v = xw[k];
            s += v.x + v.y + v.z + v.w;
        }
        asm volatile("" :: "v"(s));
    }
}

// ---------------------------------------------------------------------------
// GEMM: BM=64 x BN=256 x BK=64; 4 waves, wave w owns cols w*64..+63
// (wave-tile 64x64, acc[4][4]). A: pure-register build (R4-proven decode);
// x loaded as aligned float4 per (lane,mi) per iter. B: global->reg,
// 3 rotating buffers 2-deep. NO LDS / NO barriers / NO waitcnt pins.
// ---------------------------------------------------------------------------
__global__ __launch_bounds__(NTHR) void kan_gemm(
    const float* __restrict__ x,          // [B][D] f32
    const unsigned short* __restrict__ Vp,
    float* __restrict__ part,             // [3][8192][256] f32 (ks=1..3)
    float* __restrict__ out)              // [8192][256] f32 (ks=0 partial)
{
    const int t    = threadIdx.x;
    const int lane = t & 63;
    const int wid  = t >> 6;           // wave = col slice wid*64
    const int l15  = lane & 15;
    const int lhi  = lane >> 4;        // 0..3
    const int hi2  = lhi >> 1;         // d-sub select within pair
    const int jbase = (lhi & 1) * 4;   // dword window base of knot-half

    const int bid = (int)blockIdx.x;
    const int m8  = bid & 7;                        // == XCD (round-robin)
    const int ks  = (bid >> 3) & 3;
    const int mhi = bid >> 5;                       // 0..15
    const int mt  = m8 + 8 * mhi;                   // 0..127, mt%8==XCD
    const int bm0 = mt * BM;
    const size_t kc0 = (size_t)ks * 128;            // global 16B-chunk base

    // x row pointers: rows mi*16 + l15, d-slice base ks*64
    const float* xrow[4];
#pragma unroll
    for (int mi = 0; mi < 4; ++mi)
        xrow[mi] = x + (size_t)(bm0 + mi * 16 + l15) * D_DIM + ks * 64;

    // one x value -> lane's 4-dword A-fragment half (R4-proven decode)
    auto mkfrag = [&](float xv) -> bf16x8 {
        float xc = fminf(1.f, fmaxf(-1.f, xv));
        float tt = (xc + 1.f) * 7.5f;            // (xc - g0)/h, h = 2/15
        int li = (int)tt;
        li = li > 14 ? 14 : li;
        float w1 = tt - (float)li;
        float2 cw; cw.x = 1.f - w1; cw.y = w1;
        __hip_bfloat162 p2 = __float22bfloat162_rn(cw);   // v_cvt_pk_bf16_f32
        unsigned int pk;
        __builtin_memcpy(&pk, &p2, 4);
        unsigned long long w64 = (unsigned long long)pk << ((li & 1) << 4);
        unsigned int lo = (unsigned int)w64;
        unsigned int hi = (unsigned int)(w64 >> 32);
        int jl = (li >> 1) - jbase;              // may be -1..4 (straddle ok)
        uint4 w;
        w.x = (jl == 0) ? lo : ((jl == -1) ? hi : 0u);
        w.y = (jl == 1) ? lo : ((jl == 0)  ? hi : 0u);
        w.z = (jl == 2) ? lo : ((jl == 1)  ? hi : 0u);
        w.w = (jl == 3) ? lo : ((jl == 2)  ? hi : 0u);
        bf16x8 r;
        __builtin_memcpy(&r, &w, 16);
        return r;
    };

    // B fragment loads: frag (kh,ni): chunk kc0 + KT*8 + kh*4 + lhi,
    // col n = wid*64 + ni*16 + l15.  8 loads/iter, no duplication.
    #define LOADB(BG, KT)                                                      \
        {                                                                      \
            const unsigned short* _b =                                         \
                Vp + (kc0 + (size_t)(KT) * 8) * 2048;                          \
            _Pragma("unroll")                                                  \
            for (int kh = 0; kh < 2; ++kh)                                     \
                _Pragma("unroll")                                              \
                for (int ni = 0; ni < 4; ++ni) {                               \
                    int n = wid * 64 + ni * 16 + l15;                          \
                    BG[kh * 4 + ni] = *reinterpret_cast<const bf16x8*>(        \
                        _b + ((size_t)((kh * 4 + lhi) * 256 + n)) * 8);        \
                }                                                              \
        }

    // x loads for iter KT: one aligned float4 per mi (4 d's of the iter)
    #define LOADX(XV, KT)                                                      \
        {                                                                      \
            _Pragma("unroll")                                                  \
            for (int mi = 0; mi < 4; ++mi)                                     \
                XV[mi] = *reinterpret_cast<const float4*>(xrow[mi] + (KT) * 4);\
        }

    f32x4 acc[4][4] = {};
    bf16x8 bgA[8], bgB[8], bgC[8];   // 3 rotating B buffers (2 in flight)
    float4 xA[4], xB[4];             // x double-buffer

    // ---- prologue: 2 B-tiles + x(0), x(1) in flight
    LOADB(bgA, 0)
    LOADB(bgB, 1)
    LOADX(xA, 0)
    LOADX(xB, 1)

    // IT: compute tile KT (B from BGC_, x from XC), issue B(KT+2) into BGN2
    // and x(KT+2) into XC (freed this iter after af-build).
    #define IT(KT, BGC_, BGN2, XC, XN)                                         \
        {                                                                      \
            if ((KT) + 2 < ITERS) { LOADB(BGN2, (KT) + 2) }                    \
            bf16x8 af[4];                                                      \
            /* kh = 0: d = KT*4 + hi2 */                                       \
            _Pragma("unroll")                                                  \
            for (int mi = 0; mi < 4; ++mi)                                     \
                af[mi] = mkfrag(hi2 ? XC[mi].y : XC[mi].x);                    \
            __builtin_amdgcn_s_setprio(1);                                     \
            _Pragma("unroll")                                                  \
            for (int mi = 0; mi < 4; ++mi)                                     \
                _Pragma("unroll")                                              \
                for (int ni = 0; ni < 4; ++ni)                                 \
                    acc[mi][ni] = __builtin_amdgcn_mfma_f32_16x16x32_bf16(     \
                        af[mi], BGC_[ni], acc[mi][ni], 0, 0, 0);               \
            __builtin_amdgcn_s_setprio(0);                                     \
            /* kh = 1: d = KT*4 + 2 + hi2 */                                   \
            _Pragma("unroll")                                                  \
            for (int mi = 0; mi < 4; ++mi)                                     \
                af[mi] = mkfrag(hi2 ? XC[mi].w : XC[mi].z);                    \
            if ((KT) + 2 < ITERS) { LOADX(XC, (KT) + 2) }                      \
            __builtin_amdgcn_s_setprio(1);                                     \
            _Pragma("unroll")                                                  \
            for (int mi = 0; mi < 4; ++mi)                                     \
                _Pragma("unroll")                                              \
                for (int ni = 0; ni < 4; ++ni)                                 \
                    acc[mi][ni] = __builtin_amdgcn_mfma_f32_16x16x32_bf16(     \
                        af[mi], BGC_[4 + ni], acc[mi][ni], 0, 0, 0);           \
            __builtin_amdgcn_s_setprio(0);                                     \
        }

    // 16 iters; B rotation period 3 (2-deep); x alternates (2-deep)
    IT(0,  bgA, bgC, xA, xB)  IT(1,  bgB, bgA, xB, xA)  IT(2,  bgC, bgB, xA, xB)
    IT(3,  bgA, bgC, xB, xA)  IT(4,  bgB, bgA, xA, xB)  IT(5,  bgC, bgB, xB, xA)
    IT(6,  bgA, bgC, xA, xB)  IT(7,  bgB, bgA, xB, xA)  IT(8,  bgC, bgB, xA, xB)
    IT(9,  bgA, bgC, xB, xA)  IT(10, bgB, bgA, xA, xB)  IT(11, bgC, bgB, xB, xA)
    IT(12, bgA, bgC, xA, xB)  IT(13, bgB, bgA, xB, xA)  IT(14, bgC, bgB, xA, xB)
    IT(15, bgA, bgC, xB, xA)
    #undef IT
    #undef LOADB
    #undef LOADX

    // ---- epilogue: raw partial store (bias added in reduce)
    float* dst = (ks == 0) ? out : part + (size_t)(ks - 1) * (8192 * 256);
#pragma unroll
    for (int ni = 0; ni < 4; ++ni) {
        int col = wid * 64 + ni * 16 + l15;
#pragma unroll
        for (int mi = 0; mi < 4; ++mi) {
            f32x4 v = acc[mi][ni];
            int row0 = bm0 + mi * 16 + lhi * 4;
#pragma unroll
            for (int r = 0; r < 4; ++r)
                dst[(size_t)(row0 + r) * O_DIM + col] = v[r];
        }
    }
}

// ---------------------------------------------------------------------------
// Reduce: out += part[0..2] + skip_b, XCD-congruent mapping (mt 0..127).
// ---------------------------------------------------------------------------
__global__ __launch_bounds__(256) void kan_reduce(
    const float* __restrict__ part,   // [3][8192][256]
    const float* __restrict__ skip_b, // [256]
    float* __restrict__ out)          // [8192][256] (holds ks=0 partial)
{
    int rbid = (int)blockIdx.x;       // 0..2047
    int c    = rbid & 7;
    int tq   = rbid >> 3;             // 0..255
    int mhi  = tq >> 4;               // 0..15
    int sub  = tq & 15;               // 0..15 -> 4-row stripe
    int mt   = c + 8 * mhi;           // 0..127
    int row0 = mt * BM + sub * 4;

    int i   = (int)threadIdx.x;
    int row = row0 + (i >> 6);
    int col = (i & 63) * 4;
    size_t e = (size_t)row * O_DIM + col;

    f32x4 s = *reinterpret_cast<const f32x4*>(out + e);
    s += *reinterpret_cast<const f32x4*>(skip_b + col);
    s += *reinterpret_cast<const f32x4*>(part + e);
    s += *reinterpret_cast<const f32x4*>(part + (size_t)8192 * 256 + e);
    s += *reinterpret_cast<const f32x4*>(part + (size_t)2 * 8192 * 256 + e);
    *reinterpret_cast<f32x4*>(out + e) = s;
}

// ---------------------------------------------------------------------------
// Naive fallback (tiny workspace only) — correct, slow.
// ---------------------------------------------------------------------------
__global__ __launch_bounds__(256) void kan_naive(
    const float* __restrict__ x,
    const unsigned short* __restrict__ Vp,   // chunk-transposed
    const float* __restrict__ skip_b,
    float* __restrict__ out)
{
    int b = blockIdx.x, o = threadIdx.x;
    float acc = skip_b[o];
    for (int d = 0; d < 256; ++d) {
        float xc = fminf(1.f, fmaxf(-1.f, x[(size_t)b * 256 + d]));
        float tt = (xc + 1.f) * 7.5f;
        int li = (int)tt; li = li > 14 ? 14 : li;
        float w1 = tt - (float)li;
        int k0 = d * 16 + li;
        unsigned short u0 = Vp[((size_t)(k0 >> 3) * 256 + o) * 8 + (k0 & 7)];
        int k1 = k0 + 1;
        unsigned short u1 = Vp[((size_t)(k1 >> 3) * 256 + o) * 8 + (k1 & 7)];
        float f0 = __uint_as_float((unsigned)u0 << 16);
        float f1 = __uint_as_float((unsigned)u1 << 16);
        acc += (1.f - w1) * f0 + w1 * f1;
    }
    out[(size_t)b * 256 + o] = acc;
}

extern "C" void kernel_launch(void* const* d_in, const int* in_sizes, int n_in,
                              void* d_out, int out_size, void* d_ws, size_t ws_size,
                              hipStream_t stream) {
    const float* x      = (const float*)d_in[0];   // [8192][256]
    const float* values = (const float*)d_in[1];   // [256][256][16]
    const float* skip_w = (const float*)d_in[2];   // [256][256]
    const float* skip_b = (const float*)d_in[3];   // [256]
    const float* gknots = (const float*)d_in[4];   // [16]
    float* out = (float*)d_out;
    (void)in_sizes; (void)n_in; (void)out_size;

    unsigned short* Vp = (unsigned short*)d_ws;                          // 2 MB
    float* part = (float*)((char*)d_ws + 2u * 1024 * 1024);              // 24 MB

    kan_prep<<<dim3(512), dim3(256), 0, stream>>>(values, skip_w, gknots, x, Vp);

    const size_t need = 2u * 1024 * 1024
                      + (size_t)3 * 8192 * 256 * sizeof(float);
    if (ws_size >= need) {
        // 128 mt x 4 ks = 512 blocks = 2/CU, XCD-coherent (mt%8 == bid%8)
        kan_gemm<<<dim3(512), dim3(NTHR), 0, stream>>>(x, Vp, part, out);
        kan_reduce<<<dim3(2048), dim3(256), 0, stream>>>(part, skip_b, out);
    } else {
        kan_naive<<<dim3(8192), dim3(256), 0, stream>>>(x, Vp, skip_b, out);
    }
}

// Round 20
// 39.695 us; speedup vs baseline: 1.9071x; 1.9071x over previous
//
#include <hip/hip_runtime.h>
#include <hip/hip_bf16.h>
#include <stdint.h>

// KANLinear: y[b,o] = sum_{d,k} coeff[b,d,k]*values[o,d,k] + xc@skip_w^T + skip_b
//   Vp[o,d*16+k] = values[o,d,k] + grid[k]*skip_w[o,d]   (prep, bf16)
//   y = A @ Vp^T + skip_b  (MFMA GEMM  M=8192 N=256 K=4096)
// Round 20 (final consolidation): R17 core (best measured, 40.27us) with
//   two trims: (1) x-warm removed from prep (+8MB reads, unproven benefit);
//   (2) s_setprio removed (m190: negative on lockstep GEMM).
//   Structure: BM=128 x BN=256 x BK=64, 8 waves 2x4, wave-tile 64x64,
//   A via LDS dbuf (XOR swizzle, conflict-free), B direct L2->reg with
//   2-deep 3-buffer prefetch, KS=4 XCD-coherent, partials + reduce.

#define D_DIM  256
#define O_DIM  256
#define BM     128
#define BK     64
#define KS     4
#define ITERS  16             // (4096/KS)/BK
#define NTHR   512

typedef __attribute__((ext_vector_type(8))) short bf16x8;
typedef __attribute__((ext_vector_type(4))) float f32x4;

// ---------------------------------------------------------------------------
// Prep: Vp chunk-transposed: chunk c = kflat>>3 (16B of 8 bf16) stored at
// Vp[(c*256 + o)*8] -> GEMM B-fragment loads are 256B-coalesced.
// ---------------------------------------------------------------------------
__global__ __launch_bounds__(256) void kan_prep(
    const float* __restrict__ values,   // [O][D][K]
    const float* __restrict__ skip_w,   // [O][D]
    const float* __restrict__ gknots,   // [K]
    unsigned short* __restrict__ Vp)    // 2 MB bf16, chunk-transposed
{
    int tid = blockIdx.x * blockDim.x + threadIdx.x;    // 0..131071
    int e = tid * 8;
    int o = e >> 12;
    int kflat = e & 4095;
    float sw = skip_w[(o << 8) | (kflat >> 4)];
    int kmod = kflat & 15;                              // 0 or 8

    const float4* vp4 = reinterpret_cast<const float4*>(values + e);
    float4 v0 = vp4[0], v1 = vp4[1];
    float f[8] = {v0.x, v0.y, v0.z, v0.w, v1.x, v1.y, v1.z, v1.w};
    unsigned int w[4];
#pragma unroll
    for (int j = 0; j < 4; ++j) {
        float2 ab;
        ab.x = f[2*j]     + gknots[kmod + 2*j]     * sw;
        ab.y = f[2*j + 1] + gknots[kmod + 2*j + 1] * sw;
        __hip_bfloat162 p2 = __float22bfloat162_rn(ab);
        __builtin_memcpy(&w[j], &p2, 4);
    }
    size_t c = (size_t)(kflat >> 3) * 256 + (size_t)o;
    *reinterpret_cast<uint4*>(Vp + c * 8) = make_uint4(w[0], w[1], w[2], w[3]);
}

// ---------------------------------------------------------------------------
// GEMM: BM=128 x BN=256 x BK=64, 512 thr = 8 waves (2m x 4n), wave-tile
// 64x64 (acc[4][4]). A via LDS dbuf (XOR swizzle); B direct global->reg,
// 3 rotating buffers, 2 tiles in flight. KS=4, XCD-coherent bid map
// (mt%8 == bid%8). ks=0 -> out (raw partial), ks>0 -> part[ks-1].
// ---------------------------------------------------------------------------
__global__ __launch_bounds__(NTHR, 2) void kan_gemm(
    const float* __restrict__ x,          // [B][D] f32
    const unsigned short* __restrict__ Vp,
    float* __restrict__ part,             // [3][8192][256] f32 (ks=1..3)
    float* __restrict__ out)              // [8192][256] f32 (ks=0 partial)
{
    __shared__ unsigned short As[2][BM * BK];   // 2 x 16 KB

    const int t    = threadIdx.x;
    const int lane = t & 63;
    const int wid  = t >> 6;
    const int wm   = wid >> 2;         // 0..1  (64 rows each)
    const int wn   = wid & 3;          // 0..3  (64 cols each)
    const int l15  = lane & 15;
    const int lhi  = lane >> 4;        // 0..3

    const int bid = (int)blockIdx.x;
    const int m8  = bid & 7;                       // == XCD (round-robin)
    const int ks  = (bid >> 3) & 3;
    const int mhi = bid >> 5;                      // 0..7
    const int mt  = m8 + 8 * mhi;                  // 0..63
    const int bm0 = mt * BM;
    const size_t kc0 = (size_t)ks * 128;           // global 16B-chunk base

    const int ar = t >> 2;
    const int ad = t & 3;
    const float* xp = x + (size_t)(bm0 + ar) * D_DIM + ks * 64 + ad;

    char* arow[2] = { (char*)&As[0][0] + ar * 128, (char*)&As[1][0] + ar * 128 };
    const int ca = ((2 * ad)     ^ (ar & 7)) * 16;
    const int cb = ((2 * ad + 1) ^ (ar & 7)) * 16;

    // one x value -> 16 bf16 interp coeffs (8 dwords), pair at knots li,li+1
    auto stageA = [&](int buf, float xv) {
        float xc = fminf(1.f, fmaxf(-1.f, xv));
        float tt = (xc + 1.f) * 7.5f;            // (xc - g0)/h, h = 2/15
        int li = (int)tt;
        li = li > 14 ? 14 : li;
        float w1 = tt - (float)li;
        float2 cw; cw.x = 1.f - w1; cw.y = w1;
        __hip_bfloat162 p2 = __float22bfloat162_rn(cw);   // v_cvt_pk_bf16_f32
        unsigned int pk;
        __builtin_memcpy(&pk, &p2, 4);
        unsigned long long w64 = (unsigned long long)pk << ((li & 1) * 16);
        unsigned int lo = (unsigned int)w64;
        unsigned int hi = (unsigned int)(w64 >> 32);
        int jl = li >> 1;
        unsigned int wd[8];
#pragma unroll
        for (int j = 0; j < 8; ++j)
            wd[j] = (j == jl) ? lo : ((j == jl + 1) ? hi : 0u);
        char* a = arow[buf];
        *reinterpret_cast<uint4*>(a + ca) = make_uint4(wd[0], wd[1], wd[2], wd[3]);
        *reinterpret_cast<uint4*>(a + cb) = make_uint4(wd[4], wd[5], wd[6], wd[7]);
    };

    // B fragment loads: frag (kh, ni) at chunk kc0 + KT*8 + kh*4 + lhi,
    // column n = wn*64 + ni*16 + l15.
    #define LOADB(BG, KT)                                                      \
        {                                                                      \
            const unsigned short* _b =                                         \
                Vp + (kc0 + (size_t)(KT) * 8) * 2048;                          \
            _Pragma("unroll")                                                  \
            for (int kh = 0; kh < 2; ++kh)                                     \
                _Pragma("unroll")                                              \
                for (int ni = 0; ni < 4; ++ni) {                               \
                    int n = wn * 64 + ni * 16 + l15;                           \
                    BG[kh * 4 + ni] = *reinterpret_cast<const bf16x8*>(        \
                        _b + ((size_t)((kh * 4 + lhi) * 256 + n)) * 8);        \
                }                                                              \
        }

    f32x4 acc[4][4] = {};
    bf16x8 bgA[8], bgB[8], bgC[8];   // 3 rotating B buffers (2 in flight)

    int abyte[4], a7[4];
#pragma unroll
    for (int mi = 0; mi < 4; ++mi) {
        int m = wm * 64 + mi * 16 + l15;
        abyte[mi] = m * 128;
        a7[mi] = m & 7;
    }

    // ---- prologue: 2 B-tiles in flight, stage A(0), prefetch x(1)
    float xnxt = xp[0];
    LOADB(bgA, 0)
    LOADB(bgB, 1)
    stageA(0, xnxt);
    xnxt = xp[4];
    asm volatile("s_waitcnt lgkmcnt(0)" ::: "memory");
    __builtin_amdgcn_s_barrier();
    __builtin_amdgcn_sched_barrier(0);

    // IT(KT, CUR, BGC_, BGN2): compute tile KT from BGC_ (A-buf CUR),
    // issue B(KT+2) into BGN2 (the buffer freed 2 iters ago).
    #define IT(KT, CUR, BGC_, BGN2)                                            \
        {                                                                      \
            const bool last = (KT) == ITERS - 1;                               \
            if ((KT) + 2 < ITERS) { LOADB(BGN2, (KT) + 2) }                    \
            const char* Ab = (const char*)&As[CUR][0];                         \
            bf16x8 af[4];                                                      \
            /* kh = 0 */                                                       \
            _Pragma("unroll")                                                  \
            for (int mi = 0; mi < 4; ++mi)                                     \
                af[mi] = *reinterpret_cast<const bf16x8*>(                     \
                    Ab + abyte[mi] + ((lhi ^ a7[mi]) << 4));                   \
            _Pragma("unroll")                                                  \
            for (int mi = 0; mi < 4; ++mi)                                     \
                _Pragma("unroll")                                              \
                for (int ni = 0; ni < 4; ++ni)                                 \
                    acc[mi][ni] = __builtin_amdgcn_mfma_f32_16x16x32_bf16(     \
                        af[mi], BGC_[ni], acc[mi][ni], 0, 0, 0);               \
            /* stage next A while kh=1 reads queue */                          \
            if (!last) {                                                       \
                stageA((CUR) ^ 1, xnxt);                                       \
                if ((KT) + 2 < ITERS) xnxt = xp[((KT) + 2) * 4];               \
            }                                                                  \
            /* kh = 1 */                                                       \
            _Pragma("unroll")                                                  \
            for (int mi = 0; mi < 4; ++mi)                                     \
                af[mi] = *reinterpret_cast<const bf16x8*>(                     \
                    Ab + abyte[mi] + (((4 + lhi) ^ a7[mi]) << 4));             \
            _Pragma("unroll")                                                  \
            for (int mi = 0; mi < 4; ++mi)                                     \
                _Pragma("unroll")                                              \
                for (int ni = 0; ni < 4; ++ni)                                 \
                    acc[mi][ni] = __builtin_amdgcn_mfma_f32_16x16x32_bf16(     \
                        af[mi], BGC_[4 + ni], acc[mi][ni], 0, 0, 0);           \
            if (!last) {                                                       \
                asm volatile("s_waitcnt lgkmcnt(0)" ::: "memory");             \
                __builtin_amdgcn_s_barrier();                                  \
                __builtin_amdgcn_sched_barrier(0);                             \
            }                                                                  \
        }

    // 16 iters, buffer rotation period 3: issue (t+2)%3
    IT(0, 0, bgA, bgC)  IT(1, 1, bgB, bgA)  IT(2, 0, bgC, bgB)
    IT(3, 1, bgA, bgC)  IT(4, 0, bgB, bgA)  IT(5, 1, bgC, bgB)
    IT(6, 0, bgA, bgC)  IT(7, 1, bgB, bgA)  IT(8, 0, bgC, bgB)
    IT(9, 1, bgA, bgC)  IT(10, 0, bgB, bgA) IT(11, 1, bgC, bgB)
    IT(12, 0, bgA, bgC) IT(13, 1, bgB, bgA) IT(14, 0, bgC, bgB)
    IT(15, 1, bgA, bgC)
    #undef IT
    #undef LOADB

    // ---- epilogue: raw partial store (bias added in reduce)
    float* dst = (ks == 0) ? out : part + (size_t)(ks - 1) * (8192 * 256);
#pragma unroll
    for (int ni = 0; ni < 4; ++ni) {
        int col = wn * 64 + ni * 16 + l15;
#pragma unroll
        for (int mi = 0; mi < 4; ++mi) {
            f32x4 v = acc[mi][ni];
            int row0 = bm0 + wm * 64 + mi * 16 + lhi * 4;
#pragma unroll
            for (int r = 0; r < 4; ++r)
                dst[(size_t)(row0 + r) * O_DIM + col] = v[r];
        }
    }
}

// ---------------------------------------------------------------------------
// Reduce: out += part[0..2] + skip_b, XCD-congruent mapping.
// ---------------------------------------------------------------------------
__global__ __launch_bounds__(256) void kan_reduce(
    const float* __restrict__ part,   // [3][8192][256]
    const float* __restrict__ skip_b, // [256]
    float* __restrict__ out)          // [8192][256] (holds ks=0 partial)
{
    int rbid = (int)blockIdx.x;       // 0..2047
    int c    = rbid & 7;
    int tq   = rbid >> 3;             // 0..255
    int mhi  = tq >> 5;               // 0..7
    int sub  = tq & 31;               // 0..31
    int mt   = c + 8 * mhi;           // 0..63
    int row0 = mt * BM + sub * 4;

    int i   = (int)threadIdx.x;
    int row = row0 + (i >> 6);
    int col = (i & 63) * 4;
    size_t e = (size_t)row * O_DIM + col;

    f32x4 s = *reinterpret_cast<const f32x4*>(out + e);
    s += *reinterpret_cast<const f32x4*>(skip_b + col);
    s += *reinterpret_cast<const f32x4*>(part + e);
    s += *reinterpret_cast<const f32x4*>(part + (size_t)8192 * 256 + e);
    s += *reinterpret_cast<const f32x4*>(part + (size_t)2 * 8192 * 256 + e);
    *reinterpret_cast<f32x4*>(out + e) = s;
}

// ---------------------------------------------------------------------------
// Naive fallback (tiny workspace only) — correct, slow.
// ---------------------------------------------------------------------------
__global__ __launch_bounds__(256) void kan_naive(
    const float* __restrict__ x,
    const unsigned short* __restrict__ Vp,   // chunk-transposed
    const float* __restrict__ skip_b,
    float* __restrict__ out)
{
    int b = blockIdx.x, o = threadIdx.x;
    float acc = skip_b[o];
    for (int d = 0; d < 256; ++d) {
        float xc = fminf(1.f, fmaxf(-1.f, x[(size_t)b * 256 + d]));
        float tt = (xc + 1.f) * 7.5f;
        int li = (int)tt; li = li > 14 ? 14 : li;
        float w1 = tt - (float)li;
        int k0 = d * 16 + li;
        unsigned short u0 = Vp[((size_t)(k0 >> 3) * 256 + o) * 8 + (k0 & 7)];
        int k1 = k0 + 1;
        unsigned short u1 = Vp[((size_t)(k1 >> 3) * 256 + o) * 8 + (k1 & 7)];
        float f0 = __uint_as_float((unsigned)u0 << 16);
        float f1 = __uint_as_float((unsigned)u1 << 16);
        acc += (1.f - w1) * f0 + w1 * f1;
    }
    out[(size_t)b * 256 + o] = acc;
}

extern "C" void kernel_launch(void* const* d_in, const int* in_sizes, int n_in,
                              void* d_out, int out_size, void* d_ws, size_t ws_size,
                              hipStream_t stream) {
    const float* x      = (const float*)d_in[0];   // [8192][256]
    const float* values = (const float*)d_in[1];   // [256][256][16]
    const float* skip_w = (const float*)d_in[2];   // [256][256]
    const float* skip_b = (const float*)d_in[3];   // [256]
    const float* gknots = (const float*)d_in[4];   // [16]
    float* out = (float*)d_out;
    (void)in_sizes; (void)n_in; (void)out_size;

    unsigned short* Vp = (unsigned short*)d_ws;                          // 2 MB
    float* part = (float*)((char*)d_ws + 2u * 1024 * 1024);              // 24 MB

    kan_prep<<<dim3(512), dim3(256), 0, stream>>>(values, skip_w, gknots, Vp);

    const size_t need = 2u * 1024 * 1024
                      + (size_t)3 * 8192 * 256 * sizeof(float);
    if (ws_size >= need) {
        // 64 mt x 4 ks = 256 blocks = 1/CU, XCD-coherent (mt%8 == bid%8)
        kan_gemm<<<dim3(256), dim3(NTHR), 0, stream>>>(x, Vp, part, out);
        kan_reduce<<<dim3(2048), dim3(256), 0, stream>>>(part, skip_b, out);
    } else {
        kan_naive<<<dim3(8192), dim3(256), 0, stream>>>(x, Vp, skip_b, out);
    }
}